// Round 9
// baseline (1642.545 us; speedup 1.0000x reference)
//
#include <hip/hip_runtime.h>
#include <hip/hip_bf16.h>
#include <math.h>

typedef __attribute__((ext_vector_type(8))) short bf16x8;
typedef __attribute__((ext_vector_type(4))) float f32x4;

#define MFMA16(a, b, c) __builtin_amdgcn_mfma_f32_16x16x32_bf16((a), (b), (c), 0, 0, 0)

__device__ __forceinline__ float silu_f(float x) { return x / (1.0f + expf(-x)); }

__device__ __forceinline__ unsigned short f2bf(float f) {
  union { __hip_bfloat16 h; unsigned short u; } c;
  c.h = __float2bfloat16(f);
  return c.u;
}
__device__ __forceinline__ unsigned pk2(float a, float b) {
  return (unsigned)f2bf(a) | ((unsigned)f2bf(b) << 16);
}
__device__ __forceinline__ float bfu(unsigned short u) {
  union { unsigned u32; float f; } c;
  c.u32 = (unsigned)u << 16;
  return c.f;
}

// activation fragment (B-operand): lane holds col m=lane&15, k = ks*32 + (lane>>4)*8 ..+7
__device__ __forceinline__ bf16x8 ld_act(const unsigned short* buf, int strideB, int ks, int lane) {
  int row = lane & 15;
  int off = row * strideB + ks * 64 + ((lane >> 4) << 4);
  off ^= (row & 7) << 4;
  return *(const bf16x8*)((const char*)buf + off);
}

// weight fragment (A-operand): lane holds row n=rowbase+(lane&15); Wt row-major [n][K] bf16
__device__ __forceinline__ bf16x8 ld_w(const unsigned short* Wt, int rowbase, int strideB, int ks, int lane) {
  return *(const bf16x8*)((const char*)Wt + (size_t)(rowbase + (lane & 15)) * strideB + ks * 64 + ((lane >> 4) << 4));
}

// ============ fused weight prep: Wt[n][k] = bf16(W[k][n]) ============
__global__ void wprep_all(const float* __restrict__ W_nn, const float* __restrict__ W_ep,
                          const float* __restrict__ W_g1, const float* __restrict__ W_g2,
                          const float* __restrict__ W_ev,
                          unsigned short* __restrict__ wnn_t, unsigned short* __restrict__ wep_t,
                          unsigned short* __restrict__ wg1_t, unsigned short* __restrict__ wg2_t,
                          unsigned short* __restrict__ wev_t) {
  int idx = blockIdx.x * 256 + threadIdx.x;  // 0..32767
  if (idx < 8192) {
    int n = idx >> 7, k = idx & 127;
    wnn_t[idx] = f2bf(W_nn[k * 64 + n]);
  } else if (idx < 12288) {
    int t = idx - 8192; int n = t >> 6, k = t & 63;
    wep_t[t] = f2bf(W_ep[k * 64 + n]);
  } else if (idx < 16384) {
    int t = idx - 12288; int n = t >> 6, k = t & 63;
    wg1_t[t] = f2bf(W_g1[k * 64 + n]);
  } else if (idx < 20480) {
    int t = idx - 16384; int n = t >> 6, k = t & 63;
    wg2_t[t] = f2bf(W_g2[k * 64 + n]);
  } else if (idx < 32768) {
    int t = idx - 20480; int n = t >> 6, k = t & 63;
    wev_t[t] = f2bf(W_ev[k * 192 + n]);
  }
}

// ============ CSR build ============
__global__ void hist_kernel(const int* __restrict__ dst, int* __restrict__ cnt, int E) {
  int i = blockIdx.x * blockDim.x + threadIdx.x;
  if (i < E) atomicAdd(&cnt[dst[i]], 1);
}

// phase 1: per-block (1024) exclusive scan -> rowstart, block total -> bsum
__global__ __launch_bounds__(1024) void scan1_kernel(const int* __restrict__ cnt,
                                                     int* __restrict__ rowstart,
                                                     int* __restrict__ bsum, int N) {
  __shared__ int wsum[16];
  const int tid = threadIdx.x;
  const int wv = tid >> 6;
  const int i = blockIdx.x * 1024 + tid;
  int v = (i < N) ? cnt[i] : 0;
  int x = v;
  #pragma unroll
  for (int o = 1; o < 64; o <<= 1) {
    int y = __shfl_up(x, o);
    if ((tid & 63) >= o) x += y;
  }
  if ((tid & 63) == 63) wsum[wv] = x;
  __syncthreads();
  if (tid < 16) {
    int s = wsum[tid];
    #pragma unroll
    for (int o = 1; o < 16; o <<= 1) {
      int y = __shfl_up(s, o);
      if (tid >= o) s += y;
    }
    wsum[tid] = s;
  }
  __syncthreads();
  int woff = (wv > 0) ? wsum[wv - 1] : 0;
  if (i < N) rowstart[i] = woff + x - v;
  if (tid == 0) bsum[blockIdx.x] = wsum[15];
}

// phase 2: one wave scans block sums (exclusive, in place). nb <= 64.
__global__ void scan2_kernel(int* __restrict__ bsum, int nb) {
  const int tid = threadIdx.x;
  int v = (tid < nb) ? bsum[tid] : 0;
  int x = v;
  #pragma unroll
  for (int o = 1; o < 64; o <<= 1) {
    int y = __shfl_up(x, o);
    if (tid >= o) x += y;
  }
  if (tid < nb) bsum[tid] = x - v;
}

// phase 3: add block offsets; cursor copy; rowstart[N] = E
__global__ __launch_bounds__(1024) void scan3_kernel(int* __restrict__ rowstart,
                                                     int* __restrict__ cursor,
                                                     const int* __restrict__ bsum,
                                                     int N, int E) {
  const int i = blockIdx.x * 1024 + threadIdx.x;
  if (i < N) {
    int r = rowstart[i] + bsum[blockIdx.x];
    rowstart[i] = r;
    cursor[i] = r;
  }
  if (i == 0) rowstart[N] = E;
}

__global__ void scatter_kernel(const int* __restrict__ dst, int* __restrict__ cursor,
                               int* __restrict__ elist, int* __restrict__ epos, int E) {
  int i = blockIdx.x * blockDim.x + threadIdx.x;
  if (i < E) {
    int pos = atomicAdd(&cursor[dst[i]], 1);
    elist[pos] = i;
    epos[i] = pos;
  }
}

// ============ edge kernel: bf16 MFMA chain; raw updates as full 128B lines in SLOT order ============
// NOTE: raw slot-order stores are REGULAR stores — L2 merges the 8x16B pieces into one dirty
// line (r7: WRITE==output bytes). Making them nontemporal broke the merge (r8: +2.9GB HBM RMW).
__global__ __launch_bounds__(256, 8) void edge_kernel(
    const float* __restrict__ node_s, const float* __restrict__ node_v,
    const float* __restrict__ edge_s, const float* __restrict__ edge_v,
    const float* __restrict__ dist,   const float* __restrict__ vctr,
    const int* __restrict__ src,      const int* __restrict__ dst,
    const int* __restrict__ epos,
    const unsigned short* __restrict__ wnn_t, const float* __restrict__ b_nn,
    const unsigned short* __restrict__ wep_t, const float* __restrict__ b_ep,
    const unsigned short* __restrict__ wg1_t, const float* __restrict__ b_g1,
    const unsigned short* __restrict__ wg2_t, const float* __restrict__ b_g2,
    const unsigned short* __restrict__ wev_t, const float* __restrict__ b_ev,
    float* __restrict__ es_out, float* __restrict__ ev_out,
    unsigned short* __restrict__ raw_es, unsigned short* __restrict__ raw_ev,
    int use_raw, int E, int n_tiles)
{
  __shared__ __align__(16) unsigned short lds[4 * 2048]; // 16KB/block -> 8 blocks/CU
  const int wid  = threadIdx.x >> 6;
  const int lane = threadIdx.x & 63;
  const int tile = blockIdx.x * 4 + wid;
  if (tile >= n_tiles) return;
  const int ebase = tile * 16;
  unsigned short* bufA = lds + wid * 2048;
  const size_t Estride = (size_t)E * 64;

  const int m  = lane & 15;
  const int nb = lane >> 4;

  // ---- stage node_s[src] / node_s[dst] (bf16, swizzled) ----
  {
    const int sm = lane >> 5;
    const int kk = lane & 31;
    #pragma unroll
    for (int p = 0; p < 8; ++p) {
      int le = p * 2 + sm;
      int e = ebase + le; if (e >= E) e = E - 1;
      int s = src[e], d = dst[e];
      float2 vs = *(const float2*)(node_s + (size_t)s * 64 + 2 * kk);
      float2 vd = *(const float2*)(node_s + (size_t)d * 64 + 2 * kk);
      unsigned swz = (le & 7) << 4;
      *(unsigned*)((char*)bufA + ((le * 256 + kk * 4) ^ swz))       = pk2(vs.x, vs.y);
      *(unsigned*)((char*)bufA + ((le * 256 + 128 + kk * 4) ^ swz)) = pk2(vd.x, vd.y);
    }
  }
  __builtin_amdgcn_wave_barrier();

  const int e = (ebase + m < E) ? ebase + m : E - 1;
  const float dd_ = dist[e];
  const float cc = (dd_ < 5.0f) ? 0.5f * (cosf(3.14159265358979f * dd_ * 0.2f) + 1.0f) : 0.0f;
  const int s_nd = src[e];

  const f32x4 z4 = {0.0f, 0.0f, 0.0f, 0.0f};
  const unsigned swzm = (m & 7) << 4;

  // transpose-write lane roles (8 lanes x 16B = one full 128B row per edge)
  const int tme  = lane >> 3;
  const int tseg = lane & 7;
  int tpos0 = -1, tpos1 = -1;
  if (use_raw) {
    if (ebase + tme < E)     tpos0 = epos[ebase + tme];
    if (ebase + 8 + tme < E) tpos1 = epos[ebase + 8 + tme];
  }

  // A-fragments of [src|dst] (K=128)
  bf16x8 a0 = ld_act(bufA, 256, 0, lane), a1 = ld_act(bufA, 256, 1, lane);
  bf16x8 a2 = ld_act(bufA, 256, 2, lane), a3 = ld_act(bufA, 256, 3, lane);

  // B-fragments of edge_s (K=64) from global
  const float* esrow = edge_s + (size_t)e * 64;
  bf16x8 b0, b1;
  {
    const int k8 = (lane >> 4) << 3;
    f32x4 p0 = *(const f32x4*)(esrow + k8);
    f32x4 p1 = *(const f32x4*)(esrow + k8 + 4);
    f32x4 q0 = *(const f32x4*)(esrow + 32 + k8);
    f32x4 q1 = *(const f32x4*)(esrow + 32 + k8 + 4);
    union { bf16x8 v; uint4 u; } cb;
    cb.u.x = pk2(p0.x, p0.y); cb.u.y = pk2(p0.z, p0.w);
    cb.u.z = pk2(p1.x, p1.y); cb.u.w = pk2(p1.z, p1.w);
    b0 = cb.v;
    cb.u.x = pk2(q0.x, q0.y); cb.u.y = pk2(q0.z, q0.w);
    cb.u.z = pk2(q1.x, q1.y); cb.u.w = pk2(q1.z, q1.w);
    b1 = cb.v;
  }
  __builtin_amdgcn_wave_barrier();

  // ---- nn & ep per n-tile, fuse to em ----
  #pragma unroll
  for (int nt = 0; nt < 4; ++nt) {
    f32x4 aN = z4, aP = z4;
    aN = MFMA16(ld_w(wnn_t, nt * 16, 256, 0, lane), a0, aN);
    aN = MFMA16(ld_w(wnn_t, nt * 16, 256, 1, lane), a1, aN);
    aN = MFMA16(ld_w(wnn_t, nt * 16, 256, 2, lane), a2, aN);
    aN = MFMA16(ld_w(wnn_t, nt * 16, 256, 3, lane), a3, aN);
    aP = MFMA16(ld_w(wep_t, nt * 16, 128, 0, lane), b0, aP);
    aP = MFMA16(ld_w(wep_t, nt * 16, 128, 1, lane), b1, aP);
    f32x4 bn = *(const f32x4*)(b_nn + nt * 16 + nb * 4);
    f32x4 bp = *(const f32x4*)(b_ep + nt * 16 + nb * 4);
    float e0 = (aN.x + bn.x) * (aP.x + bp.x);
    float e1 = (aN.y + bn.y) * (aP.y + bp.y);
    float e2 = (aN.z + bn.z) * (aP.z + bp.z);
    float e3 = (aN.w + bn.w) * (aP.w + bp.w);
    uint2 w2; w2.x = pk2(e0, e1); w2.y = pk2(e2, e3);
    *(uint2*)((char*)bufA + ((m * 128 + nt * 32 + nb * 8) ^ swzm)) = w2;
  }
  __builtin_amdgcn_wave_barrier();

  // ---- h = silu(em @ W_g1 + b_g1) ----
  bf16x8 c0 = ld_act(bufA, 128, 0, lane), c1 = ld_act(bufA, 128, 1, lane);
  __builtin_amdgcn_wave_barrier();
  #pragma unroll
  for (int nt = 0; nt < 4; ++nt) {
    f32x4 aH = z4;
    aH = MFMA16(ld_w(wg1_t, nt * 16, 128, 0, lane), c0, aH);
    aH = MFMA16(ld_w(wg1_t, nt * 16, 128, 1, lane), c1, aH);
    f32x4 bg = *(const f32x4*)(b_g1 + nt * 16 + nb * 4);
    uint2 w2;
    w2.x = pk2(silu_f(aH.x + bg.x), silu_f(aH.y + bg.y));
    w2.y = pk2(silu_f(aH.z + bg.z), silu_f(aH.w + bg.w));
    *(uint2*)((char*)bufA + ((m * 128 + nt * 32 + nb * 8) ^ swzm)) = w2;
  }
  __builtin_amdgcn_wave_barrier();

  // ---- es_upd = (h @ W_g2 + b_g2) * c ; es_out ; pack -> bufA ----
  bf16x8 d0 = ld_act(bufA, 128, 0, lane), d1 = ld_act(bufA, 128, 1, lane);
  __builtin_amdgcn_wave_barrier();
  float* eorow = es_out + (size_t)e * 64;
  #pragma unroll
  for (int nt = 0; nt < 4; ++nt) {
    f32x4 aS = z4;
    aS = MFMA16(ld_w(wg2_t, nt * 16, 128, 0, lane), d0, aS);
    aS = MFMA16(ld_w(wg2_t, nt * 16, 128, 1, lane), d1, aS);
    f32x4 bg = *(const f32x4*)(b_g2 + nt * 16 + nb * 4);
    float u0 = (aS.x + bg.x) * cc, u1 = (aS.y + bg.y) * cc;
    float u2 = (aS.z + bg.z) * cc, u3 = (aS.w + bg.w) * cc;
    const int n0 = nt * 16 + nb * 4;
    uint2 w2; w2.x = pk2(u0, u1); w2.y = pk2(u2, u3);
    *(uint2*)((char*)bufA + ((m * 128 + nt * 32 + nb * 8) ^ swzm)) = w2;
    if (ebase + m < E) {
      f32x4 r = *(const f32x4*)(esrow + n0);
      f32x4 o; o.x = u0 + r.x; o.y = u1 + r.y; o.z = u2 + r.z; o.w = u3 + r.w;
      __builtin_nontemporal_store(o, (f32x4*)(eorow + n0));
    }
  }
  __builtin_amdgcn_wave_barrier();

  // ---- es_upd fragments + raw_es full-line slot-order write (REGULAR stores) ----
  bf16x8 g0 = ld_act(bufA, 128, 0, lane), g1f = ld_act(bufA, 128, 1, lane);
  if (use_raw) {
    if (tpos0 >= 0) {
      bf16x8 row = *(const bf16x8*)((const char*)bufA + ((tme * 128 + tseg * 16) ^ ((tme & 7) << 4)));
      *(bf16x8*)(raw_es + (size_t)tpos0 * 64 + tseg * 8) = row;
    }
    if (tpos1 >= 0) {
      bf16x8 row = *(const bf16x8*)((const char*)bufA + (((8 + tme) * 128 + tseg * 16) ^ (((8 + tme) & 7) << 4)));
      *(bf16x8*)(raw_es + (size_t)tpos1 * 64 + tseg * 8) = row;
    }
  }

  // ---- ev epilogue: dd-outer, RECOMPUTE W_ev MFMAs per plane (keeps VGPR low) ----
  const float* nvb = node_v + (size_t)s_nd * 192;
  const float* evb = edge_v + (size_t)e * 192;
  float* eob = ev_out + (size_t)e * 192;
  const float vnn[3] = {vctr[e * 3], vctr[e * 3 + 1], vctr[e * 3 + 2]};
  const bool live = (ebase + m < E);
  #pragma unroll
  for (int dd = 0; dd < 3; ++dd) {
    __builtin_amdgcn_wave_barrier();
    #pragma unroll
    for (int nt = 0; nt < 4; ++nt) {
      f32x4 aN = z4, aE = z4, aR = z4;
      aN = MFMA16(ld_w(wev_t,        nt * 16, 128, 0, lane), g0,  aN);
      aN = MFMA16(ld_w(wev_t,        nt * 16, 128, 1, lane), g1f, aN);
      aE = MFMA16(ld_w(wev_t,  64 + nt * 16, 128, 0, lane), g0,  aE);
      aE = MFMA16(ld_w(wev_t,  64 + nt * 16, 128, 1, lane), g1f, aE);
      aR = MFMA16(ld_w(wev_t, 128 + nt * 16, 128, 0, lane), g0,  aR);
      aR = MFMA16(ld_w(wev_t, 128 + nt * 16, 128, 1, lane), g1f, aR);
      const int n0 = nt * 16 + nb * 4;
      f32x4 bv0 = *(const f32x4*)(b_ev + n0);
      f32x4 bv1 = *(const f32x4*)(b_ev + 64 + n0);
      f32x4 bv2 = *(const f32x4*)(b_ev + 128 + n0);
      f32x4 nv = *(const f32x4*)(nvb + dd * 64 + n0);
      f32x4 ev = __builtin_nontemporal_load((const f32x4*)(evb + dd * 64 + n0));
      float eu0 = (nv.x * (aN.x + bv0.x) + ev.x * (aE.x + bv1.x) + vnn[dd] * (aR.x + bv2.x)) * cc;
      float eu1 = (nv.y * (aN.y + bv0.y) + ev.y * (aE.y + bv1.y) + vnn[dd] * (aR.y + bv2.y)) * cc;
      float eu2 = (nv.z * (aN.z + bv0.z) + ev.z * (aE.z + bv1.z) + vnn[dd] * (aR.z + bv2.z)) * cc;
      float eu3 = (nv.w * (aN.w + bv0.w) + ev.w * (aE.w + bv1.w) + vnn[dd] * (aR.w + bv2.w)) * cc;
      if (live) {
        f32x4 o; o.x = eu0 + ev.x; o.y = eu1 + ev.y; o.z = eu2 + ev.z; o.w = eu3 + ev.w;
        __builtin_nontemporal_store(o, (f32x4*)(eob + dd * 64 + n0));
      }
      uint2 w2; w2.x = pk2(eu0, eu1); w2.y = pk2(eu2, eu3);
      *(uint2*)((char*)bufA + ((m * 128 + nt * 32 + nb * 8) ^ swzm)) = w2;
    }
    __builtin_amdgcn_wave_barrier();
    if (use_raw) {
      unsigned short* plane = raw_ev + (size_t)dd * Estride;
      if (tpos0 >= 0) {
        bf16x8 row = *(const bf16x8*)((const char*)bufA + ((tme * 128 + tseg * 16) ^ ((tme & 7) << 4)));
        *(bf16x8*)(plane + (size_t)tpos0 * 64 + tseg * 8) = row;
      }
      if (tpos1 >= 0) {
        bf16x8 row = *(const bf16x8*)((const char*)bufA + (((8 + tme) * 128 + tseg * 16) ^ (((8 + tme) & 7) << 4)));
        *(bf16x8*)(plane + (size_t)tpos1 * 64 + tseg * 8) = row;
      }
    }
  }
}

// ============ node kernel: SEQUENTIAL slot-order aggregation + node update ============
__device__ __forceinline__ void ld4(const float* p, float o[4]) {
  f32x4 v = *(const f32x4*)p;
  o[0] = v.x; o[1] = v.y; o[2] = v.z; o[3] = v.w;
}

__global__ __launch_bounds__(256) void node_kernel(
    const float* __restrict__ node_s, const float* __restrict__ node_v,
    const float* __restrict__ edge_s, const float* __restrict__ edge_v,
    const float* __restrict__ es_r,   const float* __restrict__ ev_r,
    const unsigned short* __restrict__ raw_es, const unsigned short* __restrict__ raw_ev,
    const int* __restrict__ rowstart, const int* __restrict__ elist, int use_raw,
    const float* __restrict__ W_nvout,
    const float* __restrict__ W_nvc, const float* __restrict__ b_nvc,
    const float* __restrict__ W_nvp,
    const float* __restrict__ W_nsp, const float* __restrict__ b_nsp,
    const float* __restrict__ ln_g, const float* __restrict__ ln_b,
    const float* __restrict__ cn_s,
    float* __restrict__ ns_out, float* __restrict__ nv_out, int N, int E)
{
  __shared__ __align__(16) float scm[4 * 8 * 68];
  const int wid = threadIdx.x >> 6, lane = threadIdx.x & 63;
  const int n = blockIdx.x * 4 + wid;
  if (n >= N) return;
  float* S = &scm[wid * 8 * 68];

  const int rs = rowstart[n], re = rowstart[n + 1];
  float nes = 0.0f, nev0 = 0.0f, nev1 = 0.0f, nev2 = 0.0f;
  if (use_raw) {
    const size_t Estride = (size_t)E * 64;
    const unsigned short* pe = raw_es + (size_t)rs * 64 + lane;
    const unsigned short* v0 = raw_ev + (size_t)rs * 64 + lane;
    const unsigned short* v1 = v0 + Estride;
    const unsigned short* v2 = v1 + Estride;
    const int cntE = re - rs;
    int i = 0;
    for (; i + 1 < cntE; i += 2) {
      unsigned short e0 = pe[i * 64],  e1 = pe[i * 64 + 64];
      unsigned short a0 = v0[i * 64],  a1 = v0[i * 64 + 64];
      unsigned short b0 = v1[i * 64],  b1 = v1[i * 64 + 64];
      unsigned short c0 = v2[i * 64],  c1 = v2[i * 64 + 64];
      nes  += bfu(e0) + bfu(e1);
      nev0 += bfu(a0) + bfu(a1);
      nev1 += bfu(b0) + bfu(b1);
      nev2 += bfu(c0) + bfu(c1);
    }
    if (i < cntE) {
      nes  += bfu(pe[i * 64]);
      nev0 += bfu(v0[i * 64]); nev1 += bfu(v1[i * 64]); nev2 += bfu(v2[i * 64]);
    }
  } else {
    for (int idx = rs; idx < re; ++idx) {
      int e = elist[idx];
      size_t b64 = (size_t)e * 64, b192 = (size_t)e * 192;
      nes  += es_r[b64 + lane]        - edge_s[b64 + lane];
      nev0 += ev_r[b192 + lane]       - edge_v[b192 + lane];
      nev1 += ev_r[b192 + 64 + lane]  - edge_v[b192 + 64 + lane];
      nev2 += ev_r[b192 + 128 + lane] - edge_v[b192 + 128 + lane];
    }
  }
  const float inv = 1.0f / fmaxf((float)(re - rs), 1.0f);
  nes *= inv; nev0 *= inv; nev1 *= inv; nev2 *= inv;

  S[0 * 68 + lane] = nev0; S[1 * 68 + lane] = nev1;
  S[2 * 68 + lane] = nev2; S[3 * 68 + lane] = nes;
  __builtin_amdgcn_wave_barrier();

  // n_ev @ W_nvout -> o1,o2,o3
  float o1[3] = {}, o2[3] = {}, o3[3] = {};
  for (int k = 0; k < 64; k += 4) {
    float a0[4], a1[4], a2[4];
    ld4(S + 0 * 68 + k, a0); ld4(S + 1 * 68 + k, a1); ld4(S + 2 * 68 + k, a2);
    #pragma unroll
    for (int kk = 0; kk < 4; ++kk) {
      float w0 = W_nvout[(k + kk) * 192 + lane];
      float w1 = W_nvout[(k + kk) * 192 + 64 + lane];
      float w2 = W_nvout[(k + kk) * 192 + 128 + lane];
      o1[0] = fmaf(a0[kk], w0, o1[0]); o1[1] = fmaf(a1[kk], w0, o1[1]); o1[2] = fmaf(a2[kk], w0, o1[2]);
      o2[0] = fmaf(a0[kk], w1, o2[0]); o2[1] = fmaf(a1[kk], w1, o2[1]); o2[2] = fmaf(a2[kk], w1, o2[2]);
      o3[0] = fmaf(a0[kk], w2, o3[0]); o3[1] = fmaf(a1[kk], w2, o3[1]); o3[2] = fmaf(a2[kk], w2, o3[2]);
    }
  }
  float nrm = sqrtf(o3[0] * o3[0] + o3[1] * o3[1] + o3[2] * o3[2]);
  S[4 * 68 + lane] = nrm;
  __builtin_amdgcn_wave_barrier();

  // v_channel = [n_es | ||o3||] @ W_nvc + b_nvc
  float vch = 0.0f;
  for (int k = 0; k < 64; k += 4) {
    float a[4], b[4];
    ld4(S + 3 * 68 + k, a); ld4(S + 4 * 68 + k, b);
    #pragma unroll
    for (int kk = 0; kk < 4; ++kk) {
      vch = fmaf(a[kk], W_nvc[(k + kk) * 64 + lane], vch);
      vch = fmaf(b[kk], W_nvc[(64 + k + kk) * 64 + lane], vch);
    }
  }
  vch += b_nvc[lane];

  float nvu[3];
  #pragma unroll
  for (int dd = 0; dd < 3; ++dd) {
    nvu[dd] = o1[dd] * vch + o2[dd];
    S[(5 + dd) * 68 + lane] = nvu[dd];
  }
  __builtin_amdgcn_wave_barrier();

  // nvp1/nvp2 = nv_upd @ W_nvp (split)
  float p1[3] = {}, p2[3] = {};
  for (int k = 0; k < 64; k += 4) {
    float a0[4], a1[4], a2[4];
    ld4(S + 5 * 68 + k, a0); ld4(S + 6 * 68 + k, a1); ld4(S + 7 * 68 + k, a2);
    #pragma unroll
    for (int kk = 0; kk < 4; ++kk) {
      float w1 = W_nvp[(k + kk) * 128 + lane];
      float w2 = W_nvp[(k + kk) * 128 + 64 + lane];
      p1[0] = fmaf(a0[kk], w1, p1[0]); p1[1] = fmaf(a1[kk], w1, p1[1]); p1[2] = fmaf(a2[kk], w1, p1[2]);
      p2[0] = fmaf(a0[kk], w2, p2[0]); p2[1] = fmaf(a1[kk], w2, p2[1]); p2[2] = fmaf(a2[kk], w2, p2[2]);
    }
  }

  // ns1/ns2 = silu(n_es @ W_nsp + b_nsp) split
  float s1a = 0.0f, s2a = 0.0f;
  for (int k = 0; k < 64; k += 4) {
    float a[4];
    ld4(S + 3 * 68 + k, a);
    #pragma unroll
    for (int kk = 0; kk < 4; ++kk) {
      s1a = fmaf(a[kk], W_nsp[(k + kk) * 128 + lane], s1a);
      s2a = fmaf(a[kk], W_nsp[(k + kk) * 128 + 64 + lane], s2a);
    }
  }
  float s1 = silu_f(s1a + b_nsp[lane]);
  float s2 = silu_f(s2a + b_nsp[64 + lane]);

  float nvdot = p1[0] * p2[0] + p1[1] * p2[1] + p1[2] * p2[2];
  float nsu = nvdot * s1 + s2;

  // LayerNorm over 64 features (wave-wide)
  float xs = nsu + node_s[n * 64 + lane];
  float sum = xs, sumsq = xs * xs;
  #pragma unroll
  for (int o = 32; o; o >>= 1) {
    sum += __shfl_xor(sum, o);
    sumsq += __shfl_xor(sumsq, o);
  }
  float mu = sum * (1.0f / 64.0f);
  float var = sumsq * (1.0f / 64.0f) - mu * mu;
  ns_out[n * 64 + lane] = (xs - mu) * rsqrtf(var + 1e-5f) * ln_g[lane] + ln_b[lane];

  // CoorsNorm over 3D axis (lane-local)
  float vv[3];
  #pragma unroll
  for (int dd = 0; dd < 3; ++dd) vv[dd] = nvu[dd] + node_v[n * 192 + dd * 64 + lane];
  float vn2 = sqrtf(vv[0] * vv[0] + vv[1] * vv[1] + vv[2] * vv[2]);
  float scale = cn_s[lane] / fmaxf(vn2, 1e-8f);
  #pragma unroll
  for (int dd = 0; dd < 3; ++dd)
    nv_out[n * 192 + dd * 64 + lane] = vv[dd] * scale;
}

extern "C" void kernel_launch(void* const* d_in, const int* in_sizes, int n_in,
                              void* d_out, int out_size, void* d_ws, size_t ws_size,
                              hipStream_t stream) {
  const float* node_s = (const float*)d_in[0];
  const float* node_v = (const float*)d_in[1];
  const float* edge_s = (const float*)d_in[2];
  const float* edge_v = (const float*)d_in[3];
  const float* dist   = (const float*)d_in[4];
  const float* vctr   = (const float*)d_in[5];
  const int*   src    = (const int*)d_in[6];
  const int*   dst    = (const int*)d_in[7];
  const float* W_nn = (const float*)d_in[8];  const float* b_nn = (const float*)d_in[9];
  const float* W_ep = (const float*)d_in[10]; const float* b_ep = (const float*)d_in[11];
  const float* W_g1 = (const float*)d_in[12]; const float* b_g1 = (const float*)d_in[13];
  const float* W_g2 = (const float*)d_in[14]; const float* b_g2 = (const float*)d_in[15];
  const float* W_ev = (const float*)d_in[16]; const float* b_ev = (const float*)d_in[17];
  const float* W_nvout = (const float*)d_in[18];
  const float* W_nvc = (const float*)d_in[19]; const float* b_nvc = (const float*)d_in[20];
  const float* W_nvp = (const float*)d_in[21];
  const float* W_nsp = (const float*)d_in[22]; const float* b_nsp = (const float*)d_in[23];
  const float* ln_g = (const float*)d_in[24]; const float* ln_b = (const float*)d_in[25];
  const float* cn_s = (const float*)d_in[26];

  const int N = in_sizes[0] / 64;
  const int E = in_sizes[2] / 64;

  float* out    = (float*)d_out;
  float* ns_out = out;
  float* nv_out = out + (size_t)N * 64;
  float* es_out = out + (size_t)N * 256;
  float* ev_out = out + (size_t)N * 256 + (size_t)E * 64;

  // ws layout: ints | bf16 weights | raw bf16 updates (CSR-SLOT order; ev as 3 dd-planes)
  int* cnt      = (int*)d_ws;          // N (histogram, then cursor)
  int* rowstart = cnt + N;             // N+1
  int* epos     = rowstart + N + 1;    // E
  int* elist    = epos + E;            // E (fallback only)
  int* bsum     = elist + E;           // 64 (scan block sums)
  unsigned short* wnn_t = (unsigned short*)(bsum + 64);  // 64x128
  unsigned short* wep_t = wnn_t + 64 * 128;              // 64x64
  unsigned short* wg1_t = wep_t + 64 * 64;
  unsigned short* wg2_t = wg1_t + 64 * 64;
  unsigned short* wev_t = wg2_t + 64 * 64;               // 192x64
  size_t wend = (size_t)((char*)(wev_t + 192 * 64) - (char*)d_ws);
  size_t rawofs = (wend + 255) & ~(size_t)255;
  unsigned short* raw_es = (unsigned short*)((char*)d_ws + rawofs);  // E*64
  unsigned short* raw_ev = raw_es + (size_t)E * 64;                  // 3 * E*64 (dd-planes)
  size_t need = rawofs + (size_t)E * 256 * sizeof(unsigned short);
  int use_raw = (ws_size >= need) ? 1 : 0;

  const int nscan = (N + 1023) / 1024;

  hipMemsetAsync(cnt, 0, (size_t)N * sizeof(int), stream);
  hist_kernel<<<(E + 255) / 256, 256, 0, stream>>>(dst, cnt, E);
  scan1_kernel<<<nscan, 1024, 0, stream>>>(cnt, rowstart, bsum, N);
  scan2_kernel<<<1, 64, 0, stream>>>(bsum, nscan);
  scan3_kernel<<<nscan, 1024, 0, stream>>>(rowstart, cnt, bsum, N, E);
  scatter_kernel<<<(E + 255) / 256, 256, 0, stream>>>(dst, cnt, elist, epos, E);

  wprep_all<<<128, 256, 0, stream>>>(W_nn, W_ep, W_g1, W_g2, W_ev,
                                     wnn_t, wep_t, wg1_t, wg2_t, wev_t);

  int n_tiles = (E + 15) / 16;
  edge_kernel<<<(n_tiles + 3) / 4, 256, 0, stream>>>(
      node_s, node_v, edge_s, edge_v, dist, vctr, src, dst, epos,
      wnn_t, b_nn, wep_t, b_ep, wg1_t, b_g1, wg2_t, b_g2, wev_t, b_ev,
      es_out, ev_out, raw_es, raw_ev, use_raw, E, n_tiles);

  node_kernel<<<(N + 3) / 4, 256, 0, stream>>>(
      node_s, node_v, edge_s, edge_v, es_out, ev_out, raw_es, raw_ev,
      rowstart, elist, use_raw,
      W_nvout, W_nvc, b_nvc, W_nvp, W_nsp, b_nsp,
      ln_g, ln_b, cn_s, ns_out, nv_out, N, E);
}

// Round 10
// 1554.201 us; speedup vs baseline: 1.0568x; 1.0568x over previous
//
#include <hip/hip_runtime.h>
#include <hip/hip_bf16.h>
#include <math.h>

typedef __attribute__((ext_vector_type(8))) short bf16x8;
typedef __attribute__((ext_vector_type(4))) float f32x4;

#define MFMA16(a, b, c) __builtin_amdgcn_mfma_f32_16x16x32_bf16((a), (b), (c), 0, 0, 0)

__device__ __forceinline__ float silu_f(float x) { return x / (1.0f + expf(-x)); }

__device__ __forceinline__ unsigned short f2bf(float f) {
  union { __hip_bfloat16 h; unsigned short u; } c;
  c.h = __float2bfloat16(f);
  return c.u;
}
__device__ __forceinline__ unsigned pk2(float a, float b) {
  return (unsigned)f2bf(a) | ((unsigned)f2bf(b) << 16);
}
__device__ __forceinline__ float bfu(unsigned short u) {
  union { unsigned u32; float f; } c;
  c.u32 = (unsigned)u << 16;
  return c.f;
}

// activation fragment (B-operand): lane holds col m=lane&15, k = ks*32 + (lane>>4)*8 ..+7
__device__ __forceinline__ bf16x8 ld_act(const unsigned short* buf, int strideB, int ks, int lane) {
  int row = lane & 15;
  int off = row * strideB + ks * 64 + ((lane >> 4) << 4);
  off ^= (row & 7) << 4;
  return *(const bf16x8*)((const char*)buf + off);
}

// weight fragment (A-operand): lane holds row n=rowbase+(lane&15); Wt row-major [n][K] bf16
__device__ __forceinline__ bf16x8 ld_w(const unsigned short* Wt, int rowbase, int strideB, int ks, int lane) {
  return *(const bf16x8*)((const char*)Wt + (size_t)(rowbase + (lane & 15)) * strideB + ks * 64 + ((lane >> 4) << 4));
}

// ============ fused weight prep: Wt[n][k] = bf16(W[k][n]) ============
__global__ void wprep_all(const float* __restrict__ W_nn, const float* __restrict__ W_ep,
                          const float* __restrict__ W_g1, const float* __restrict__ W_g2,
                          const float* __restrict__ W_ev,
                          unsigned short* __restrict__ wnn_t, unsigned short* __restrict__ wep_t,
                          unsigned short* __restrict__ wg1_t, unsigned short* __restrict__ wg2_t,
                          unsigned short* __restrict__ wev_t) {
  int idx = blockIdx.x * 256 + threadIdx.x;  // 0..32767
  if (idx < 8192) {
    int n = idx >> 7, k = idx & 127;
    wnn_t[idx] = f2bf(W_nn[k * 64 + n]);
  } else if (idx < 12288) {
    int t = idx - 8192; int n = t >> 6, k = t & 63;
    wep_t[t] = f2bf(W_ep[k * 64 + n]);
  } else if (idx < 16384) {
    int t = idx - 12288; int n = t >> 6, k = t & 63;
    wg1_t[t] = f2bf(W_g1[k * 64 + n]);
  } else if (idx < 20480) {
    int t = idx - 16384; int n = t >> 6, k = t & 63;
    wg2_t[t] = f2bf(W_g2[k * 64 + n]);
  } else if (idx < 32768) {
    int t = idx - 20480; int n = t >> 6, k = t & 63;
    wev_t[t] = f2bf(W_ev[k * 192 + n]);
  }
}

// ============ CSR build ============
__global__ void hist_kernel(const int* __restrict__ dst, int* __restrict__ cnt, int E) {
  int i = blockIdx.x * blockDim.x + threadIdx.x;
  if (i < E) atomicAdd(&cnt[dst[i]], 1);
}

__global__ __launch_bounds__(1024) void scan1_kernel(const int* __restrict__ cnt,
                                                     int* __restrict__ rowstart,
                                                     int* __restrict__ bsum, int N) {
  __shared__ int wsum[16];
  const int tid = threadIdx.x;
  const int wv = tid >> 6;
  const int i = blockIdx.x * 1024 + tid;
  int v = (i < N) ? cnt[i] : 0;
  int x = v;
  #pragma unroll
  for (int o = 1; o < 64; o <<= 1) {
    int y = __shfl_up(x, o);
    if ((tid & 63) >= o) x += y;
  }
  if ((tid & 63) == 63) wsum[wv] = x;
  __syncthreads();
  if (tid < 16) {
    int s = wsum[tid];
    #pragma unroll
    for (int o = 1; o < 16; o <<= 1) {
      int y = __shfl_up(s, o);
      if (tid >= o) s += y;
    }
    wsum[tid] = s;
  }
  __syncthreads();
  int woff = (wv > 0) ? wsum[wv - 1] : 0;
  if (i < N) rowstart[i] = woff + x - v;
  if (tid == 0) bsum[blockIdx.x] = wsum[15];
}

__global__ void scan2_kernel(int* __restrict__ bsum, int nb) {
  const int tid = threadIdx.x;
  int v = (tid < nb) ? bsum[tid] : 0;
  int x = v;
  #pragma unroll
  for (int o = 1; o < 64; o <<= 1) {
    int y = __shfl_up(x, o);
    if (tid >= o) x += y;
  }
  if (tid < nb) bsum[tid] = x - v;
}

__global__ __launch_bounds__(1024) void scan3_kernel(int* __restrict__ rowstart,
                                                     int* __restrict__ cursor,
                                                     const int* __restrict__ bsum,
                                                     int N, int E) {
  const int i = blockIdx.x * 1024 + threadIdx.x;
  if (i < N) {
    int r = rowstart[i] + bsum[blockIdx.x];
    rowstart[i] = r;
    cursor[i] = r;
  }
  if (i == 0) rowstart[N] = E;
}

__global__ void scatter_kernel(const int* __restrict__ dst, int* __restrict__ cursor,
                               int* __restrict__ elist, int* __restrict__ epos, int E) {
  int i = blockIdx.x * blockDim.x + threadIdx.x;
  if (i < E) {
    int pos = atomicAdd(&cursor[dst[i]], 1);
    elist[pos] = i;
    epos[i] = pos;
  }
}

// ============ edge kernel: low-VGPR phase-ping-pong; raw 128B-line slot-order writes ============
// Fragments are RE-READ from LDS per use (LDS can't spill). Raw stores are REGULAR stores
// (L2 merges full lines). Spill lesson (r8/r9): launch_bounds below true pressure -> scratch
// traffic x loop-trip-count (= +2.9GB HBM).
__global__ __launch_bounds__(256, 6) void edge_kernel(
    const float* __restrict__ node_s, const float* __restrict__ node_v,
    const float* __restrict__ edge_s, const float* __restrict__ edge_v,
    const float* __restrict__ dist,   const float* __restrict__ vctr,
    const int* __restrict__ src,      const int* __restrict__ dst,
    const int* __restrict__ epos,
    const unsigned short* __restrict__ wnn_t, const float* __restrict__ b_nn,
    const unsigned short* __restrict__ wep_t, const float* __restrict__ b_ep,
    const unsigned short* __restrict__ wg1_t, const float* __restrict__ b_g1,
    const unsigned short* __restrict__ wg2_t, const float* __restrict__ b_g2,
    const unsigned short* __restrict__ wev_t, const float* __restrict__ b_ev,
    float* __restrict__ es_out, float* __restrict__ ev_out,
    unsigned short* __restrict__ raw_es, unsigned short* __restrict__ raw_ev,
    int use_raw, int E, int n_tiles)
{
  __shared__ __align__(16) unsigned short lds[4 * 3072]; // bufA 4KB + bufB 2KB per wave = 24KB/block
  const int wid  = threadIdx.x >> 6;
  const int lane = threadIdx.x & 63;
  const int tile = blockIdx.x * 4 + wid;
  if (tile >= n_tiles) return;
  const int ebase = tile * 16;
  unsigned short* bufA = lds + wid * 3072;   // [16][128] node_s pair; later h / ev_upd staging
  unsigned short* bufB = bufA + 2048;        // [16][64]  edge_s; later em / es_upd
  const size_t Estride = (size_t)E * 64;

  const int m  = lane & 15;
  const int nb = lane >> 4;

  // ---- stage node_s[src]->bufA lo, node_s[dst]->bufA hi, edge_s->bufB ----
  {
    const int sm = lane >> 5;
    const int kk = lane & 31;
    #pragma unroll
    for (int p = 0; p < 8; ++p) {
      int le = p * 2 + sm;
      int e = ebase + le; if (e >= E) e = E - 1;
      int s = src[e], d = dst[e];
      float2 vs = *(const float2*)(node_s + (size_t)s * 64 + 2 * kk);
      float2 vd = *(const float2*)(node_s + (size_t)d * 64 + 2 * kk);
      float2 ve = *(const float2*)(edge_s + (size_t)e * 64 + 2 * kk);
      unsigned swz = (le & 7) << 4;
      *(unsigned*)((char*)bufA + ((le * 256 + kk * 4) ^ swz))       = pk2(vs.x, vs.y);
      *(unsigned*)((char*)bufA + ((le * 256 + 128 + kk * 4) ^ swz)) = pk2(vd.x, vd.y);
      *(unsigned*)((char*)bufB + ((le * 128 + kk * 4) ^ swz))       = pk2(ve.x, ve.y);
    }
  }
  __builtin_amdgcn_wave_barrier();

  const int e = (ebase + m < E) ? ebase + m : E - 1;
  const float dd_ = dist[e];
  const float cc = (dd_ < 5.0f) ? 0.5f * (cosf(3.14159265358979f * dd_ * 0.2f) + 1.0f) : 0.0f;
  const int s_nd = src[e];

  const f32x4 z4 = {0.0f, 0.0f, 0.0f, 0.0f};
  const unsigned swzm = (m & 7) << 4;

  // transpose-write lane roles (8 lanes x 16B = one full 128B row per edge)
  const int tme  = lane >> 3;
  const int tseg = lane & 7;
  int tpos0 = -1, tpos1 = -1;
  if (use_raw) {
    if (ebase + tme < E)     tpos0 = epos[ebase + tme];
    if (ebase + 8 + tme < E) tpos1 = epos[ebase + 8 + tme];
  }

  // ---- ep FIRST: accP[nt] = edge_s @ W_ep + b_ep (fragments from bufB, dropped after) ----
  f32x4 accP[4];
  {
    bf16x8 b0 = ld_act(bufB, 128, 0, lane), b1 = ld_act(bufB, 128, 1, lane);
    #pragma unroll
    for (int nt = 0; nt < 4; ++nt) {
      f32x4 aP = z4;
      aP = MFMA16(ld_w(wep_t, nt * 16, 128, 0, lane), b0, aP);
      aP = MFMA16(ld_w(wep_t, nt * 16, 128, 1, lane), b1, aP);
      f32x4 bp = *(const f32x4*)(b_ep + nt * 16 + nb * 4);
      aP.x += bp.x; aP.y += bp.y; aP.z += bp.z; aP.w += bp.w;
      accP[nt] = aP;
    }
  }

  // ---- nn per nt (fragments re-read from bufA per use), em -> bufB (edge_s dead) ----
  #pragma unroll
  for (int nt = 0; nt < 4; ++nt) {
    f32x4 aN = z4;
    aN = MFMA16(ld_w(wnn_t, nt * 16, 256, 0, lane), ld_act(bufA, 256, 0, lane), aN);
    aN = MFMA16(ld_w(wnn_t, nt * 16, 256, 1, lane), ld_act(bufA, 256, 1, lane), aN);
    aN = MFMA16(ld_w(wnn_t, nt * 16, 256, 2, lane), ld_act(bufA, 256, 2, lane), aN);
    aN = MFMA16(ld_w(wnn_t, nt * 16, 256, 3, lane), ld_act(bufA, 256, 3, lane), aN);
    f32x4 bn = *(const f32x4*)(b_nn + nt * 16 + nb * 4);
    float e0 = (aN.x + bn.x) * accP[nt].x;
    float e1 = (aN.y + bn.y) * accP[nt].y;
    float e2 = (aN.z + bn.z) * accP[nt].z;
    float e3 = (aN.w + bn.w) * accP[nt].w;
    uint2 w2; w2.x = pk2(e0, e1); w2.y = pk2(e2, e3);
    *(uint2*)((char*)bufB + ((m * 128 + nt * 32 + nb * 8) ^ swzm)) = w2;
  }
  __builtin_amdgcn_wave_barrier();

  // ---- h = silu(em @ W_g1 + b_g1): read bufB, write bufA-lo (node_s dead) ----
  #pragma unroll
  for (int nt = 0; nt < 4; ++nt) {
    f32x4 aH = z4;
    aH = MFMA16(ld_w(wg1_t, nt * 16, 128, 0, lane), ld_act(bufB, 128, 0, lane), aH);
    aH = MFMA16(ld_w(wg1_t, nt * 16, 128, 1, lane), ld_act(bufB, 128, 1, lane), aH);
    f32x4 bg = *(const f32x4*)(b_g1 + nt * 16 + nb * 4);
    uint2 w2;
    w2.x = pk2(silu_f(aH.x + bg.x), silu_f(aH.y + bg.y));
    w2.y = pk2(silu_f(aH.z + bg.z), silu_f(aH.w + bg.w));
    *(uint2*)((char*)bufA + ((m * 128 + nt * 32 + nb * 8) ^ swzm)) = w2;
  }
  __builtin_amdgcn_wave_barrier();

  // ---- es_upd = (h @ W_g2 + b_g2)*c: read bufA-lo, write bufB (em dead); es_out store ----
  const float* esrow = edge_s + (size_t)e * 64;
  float* eorow = es_out + (size_t)e * 64;
  #pragma unroll
  for (int nt = 0; nt < 4; ++nt) {
    f32x4 aS = z4;
    aS = MFMA16(ld_w(wg2_t, nt * 16, 128, 0, lane), ld_act(bufA, 128, 0, lane), aS);
    aS = MFMA16(ld_w(wg2_t, nt * 16, 128, 1, lane), ld_act(bufA, 128, 1, lane), aS);
    f32x4 bg = *(const f32x4*)(b_g2 + nt * 16 + nb * 4);
    float u0 = (aS.x + bg.x) * cc, u1 = (aS.y + bg.y) * cc;
    float u2 = (aS.z + bg.z) * cc, u3 = (aS.w + bg.w) * cc;
    const int n0 = nt * 16 + nb * 4;
    uint2 w2; w2.x = pk2(u0, u1); w2.y = pk2(u2, u3);
    *(uint2*)((char*)bufB + ((m * 128 + nt * 32 + nb * 8) ^ swzm)) = w2;
    if (ebase + m < E) {
      f32x4 r = *(const f32x4*)(esrow + n0);
      f32x4 o; o.x = u0 + r.x; o.y = u1 + r.y; o.z = u2 + r.z; o.w = u3 + r.w;
      __builtin_nontemporal_store(o, (f32x4*)(eorow + n0));
    }
  }
  __builtin_amdgcn_wave_barrier();

  // ---- raw_es full-line slot-order write from bufB (REGULAR stores) ----
  if (use_raw) {
    if (tpos0 >= 0) {
      bf16x8 row = *(const bf16x8*)((const char*)bufB + ((tme * 128 + tseg * 16) ^ ((tme & 7) << 4)));
      *(bf16x8*)(raw_es + (size_t)tpos0 * 64 + tseg * 8) = row;
    }
    if (tpos1 >= 0) {
      bf16x8 row = *(const bf16x8*)((const char*)bufB + (((8 + tme) * 128 + tseg * 16) ^ (((8 + tme) & 7) << 4)));
      *(bf16x8*)(raw_es + (size_t)tpos1 * 64 + tseg * 8) = row;
    }
  }

  // ---- ev epilogue: dd-outer, recompute per plane; es_upd fragments from bufB per nt ----
  const float* nvb = node_v + (size_t)s_nd * 192;
  const float* evb = edge_v + (size_t)e * 192;
  float* eob = ev_out + (size_t)e * 192;
  const float vnn[3] = {vctr[e * 3], vctr[e * 3 + 1], vctr[e * 3 + 2]};
  const bool live = (ebase + m < E);
  #pragma unroll
  for (int dd = 0; dd < 3; ++dd) {
    __builtin_amdgcn_wave_barrier();
    #pragma unroll
    for (int nt = 0; nt < 4; ++nt) {
      bf16x8 g0 = ld_act(bufB, 128, 0, lane), g1f = ld_act(bufB, 128, 1, lane);
      f32x4 aN = z4, aE = z4, aR = z4;
      aN = MFMA16(ld_w(wev_t,        nt * 16, 128, 0, lane), g0,  aN);
      aN = MFMA16(ld_w(wev_t,        nt * 16, 128, 1, lane), g1f, aN);
      aE = MFMA16(ld_w(wev_t,  64 + nt * 16, 128, 0, lane), g0,  aE);
      aE = MFMA16(ld_w(wev_t,  64 + nt * 16, 128, 1, lane), g1f, aE);
      aR = MFMA16(ld_w(wev_t, 128 + nt * 16, 128, 0, lane), g0,  aR);
      aR = MFMA16(ld_w(wev_t, 128 + nt * 16, 128, 1, lane), g1f, aR);
      const int n0 = nt * 16 + nb * 4;
      f32x4 bv0 = *(const f32x4*)(b_ev + n0);
      f32x4 bv1 = *(const f32x4*)(b_ev + 64 + n0);
      f32x4 bv2 = *(const f32x4*)(b_ev + 128 + n0);
      f32x4 nv = *(const f32x4*)(nvb + dd * 64 + n0);
      f32x4 ev = __builtin_nontemporal_load((const f32x4*)(evb + dd * 64 + n0));
      float eu0 = (nv.x * (aN.x + bv0.x) + ev.x * (aE.x + bv1.x) + vnn[dd] * (aR.x + bv2.x)) * cc;
      float eu1 = (nv.y * (aN.y + bv0.y) + ev.y * (aE.y + bv1.y) + vnn[dd] * (aR.y + bv2.y)) * cc;
      float eu2 = (nv.z * (aN.z + bv0.z) + ev.z * (aE.z + bv1.z) + vnn[dd] * (aR.z + bv2.z)) * cc;
      float eu3 = (nv.w * (aN.w + bv0.w) + ev.w * (aE.w + bv1.w) + vnn[dd] * (aR.w + bv2.w)) * cc;
      if (live) {
        f32x4 o; o.x = eu0 + ev.x; o.y = eu1 + ev.y; o.z = eu2 + ev.z; o.w = eu3 + ev.w;
        __builtin_nontemporal_store(o, (f32x4*)(eob + dd * 64 + n0));
      }
      uint2 w2; w2.x = pk2(eu0, eu1); w2.y = pk2(eu2, eu3);
      *(uint2*)((char*)bufA + ((m * 128 + nt * 32 + nb * 8) ^ swzm)) = w2;
    }
    __builtin_amdgcn_wave_barrier();
    if (use_raw) {
      unsigned short* plane = raw_ev + (size_t)dd * Estride;
      if (tpos0 >= 0) {
        bf16x8 row = *(const bf16x8*)((const char*)bufA + ((tme * 128 + tseg * 16) ^ ((tme & 7) << 4)));
        *(bf16x8*)(plane + (size_t)tpos0 * 64 + tseg * 8) = row;
      }
      if (tpos1 >= 0) {
        bf16x8 row = *(const bf16x8*)((const char*)bufA + (((8 + tme) * 128 + tseg * 16) ^ (((8 + tme) & 7) << 4)));
        *(bf16x8*)(plane + (size_t)tpos1 * 64 + tseg * 8) = row;
      }
    }
  }
}

// ============ node kernel: SEQUENTIAL slot-order aggregation + node update ============
__device__ __forceinline__ void ld4(const float* p, float o[4]) {
  f32x4 v = *(const f32x4*)p;
  o[0] = v.x; o[1] = v.y; o[2] = v.z; o[3] = v.w;
}

__global__ __launch_bounds__(256) void node_kernel(
    const float* __restrict__ node_s, const float* __restrict__ node_v,
    const float* __restrict__ edge_s, const float* __restrict__ edge_v,
    const float* __restrict__ es_r,   const float* __restrict__ ev_r,
    const unsigned short* __restrict__ raw_es, const unsigned short* __restrict__ raw_ev,
    const int* __restrict__ rowstart, const int* __restrict__ elist, int use_raw,
    const float* __restrict__ W_nvout,
    const float* __restrict__ W_nvc, const float* __restrict__ b_nvc,
    const float* __restrict__ W_nvp,
    const float* __restrict__ W_nsp, const float* __restrict__ b_nsp,
    const float* __restrict__ ln_g, const float* __restrict__ ln_b,
    const float* __restrict__ cn_s,
    float* __restrict__ ns_out, float* __restrict__ nv_out, int N, int E)
{
  __shared__ __align__(16) float scm[4 * 8 * 68];
  const int wid = threadIdx.x >> 6, lane = threadIdx.x & 63;
  const int n = blockIdx.x * 4 + wid;
  if (n >= N) return;
  float* S = &scm[wid * 8 * 68];

  const int rs = rowstart[n], re = rowstart[n + 1];
  float nes = 0.0f, nev0 = 0.0f, nev1 = 0.0f, nev2 = 0.0f;
  if (use_raw) {
    const size_t Estride = (size_t)E * 64;
    const unsigned short* pe = raw_es + (size_t)rs * 64 + lane;
    const unsigned short* v0 = raw_ev + (size_t)rs * 64 + lane;
    const unsigned short* v1 = v0 + Estride;
    const unsigned short* v2 = v1 + Estride;
    const int cntE = re - rs;
    int i = 0;
    for (; i + 1 < cntE; i += 2) {
      unsigned short e0 = pe[i * 64],  e1 = pe[i * 64 + 64];
      unsigned short a0 = v0[i * 64],  a1 = v0[i * 64 + 64];
      unsigned short b0 = v1[i * 64],  b1 = v1[i * 64 + 64];
      unsigned short c0 = v2[i * 64],  c1 = v2[i * 64 + 64];
      nes  += bfu(e0) + bfu(e1);
      nev0 += bfu(a0) + bfu(a1);
      nev1 += bfu(b0) + bfu(b1);
      nev2 += bfu(c0) + bfu(c1);
    }
    if (i < cntE) {
      nes  += bfu(pe[i * 64]);
      nev0 += bfu(v0[i * 64]); nev1 += bfu(v1[i * 64]); nev2 += bfu(v2[i * 64]);
    }
  } else {
    for (int idx = rs; idx < re; ++idx) {
      int e = elist[idx];
      size_t b64 = (size_t)e * 64, b192 = (size_t)e * 192;
      nes  += es_r[b64 + lane]        - edge_s[b64 + lane];
      nev0 += ev_r[b192 + lane]       - edge_v[b192 + lane];
      nev1 += ev_r[b192 + 64 + lane]  - edge_v[b192 + 64 + lane];
      nev2 += ev_r[b192 + 128 + lane] - edge_v[b192 + 128 + lane];
    }
  }
  const float inv = 1.0f / fmaxf((float)(re - rs), 1.0f);
  nes *= inv; nev0 *= inv; nev1 *= inv; nev2 *= inv;

  S[0 * 68 + lane] = nev0; S[1 * 68 + lane] = nev1;
  S[2 * 68 + lane] = nev2; S[3 * 68 + lane] = nes;
  __builtin_amdgcn_wave_barrier();

  // n_ev @ W_nvout -> o1,o2,o3
  float o1[3] = {}, o2[3] = {}, o3[3] = {};
  for (int k = 0; k < 64; k += 4) {
    float a0[4], a1[4], a2[4];
    ld4(S + 0 * 68 + k, a0); ld4(S + 1 * 68 + k, a1); ld4(S + 2 * 68 + k, a2);
    #pragma unroll
    for (int kk = 0; kk < 4; ++kk) {
      float w0 = W_nvout[(k + kk) * 192 + lane];
      float w1 = W_nvout[(k + kk) * 192 + 64 + lane];
      float w2 = W_nvout[(k + kk) * 192 + 128 + lane];
      o1[0] = fmaf(a0[kk], w0, o1[0]); o1[1] = fmaf(a1[kk], w0, o1[1]); o1[2] = fmaf(a2[kk], w0, o1[2]);
      o2[0] = fmaf(a0[kk], w1, o2[0]); o2[1] = fmaf(a1[kk], w1, o2[1]); o2[2] = fmaf(a2[kk], w1, o2[2]);
      o3[0] = fmaf(a0[kk], w2, o3[0]); o3[1] = fmaf(a1[kk], w2, o3[1]); o3[2] = fmaf(a2[kk], w2, o3[2]);
    }
  }
  float nrm = sqrtf(o3[0] * o3[0] + o3[1] * o3[1] + o3[2] * o3[2]);
  S[4 * 68 + lane] = nrm;
  __builtin_amdgcn_wave_barrier();

  // v_channel = [n_es | ||o3||] @ W_nvc + b_nvc
  float vch = 0.0f;
  for (int k = 0; k < 64; k += 4) {
    float a[4], b[4];
    ld4(S + 3 * 68 + k, a); ld4(S + 4 * 68 + k, b);
    #pragma unroll
    for (int kk = 0; kk < 4; ++kk) {
      vch = fmaf(a[kk], W_nvc[(k + kk) * 64 + lane], vch);
      vch = fmaf(b[kk], W_nvc[(64 + k + kk) * 64 + lane], vch);
    }
  }
  vch += b_nvc[lane];

  float nvu[3];
  #pragma unroll
  for (int dd = 0; dd < 3; ++dd) {
    nvu[dd] = o1[dd] * vch + o2[dd];
    S[(5 + dd) * 68 + lane] = nvu[dd];
  }
  __builtin_amdgcn_wave_barrier();

  // nvp1/nvp2 = nv_upd @ W_nvp (split)
  float p1[3] = {}, p2[3] = {};
  for (int k = 0; k < 64; k += 4) {
    float a0[4], a1[4], a2[4];
    ld4(S + 5 * 68 + k, a0); ld4(S + 6 * 68 + k, a1); ld4(S + 7 * 68 + k, a2);
    #pragma unroll
    for (int kk = 0; kk < 4; ++kk) {
      float w1 = W_nvp[(k + kk) * 128 + lane];
      float w2 = W_nvp[(k + kk) * 128 + 64 + lane];
      p1[0] = fmaf(a0[kk], w1, p1[0]); p1[1] = fmaf(a1[kk], w1, p1[1]); p1[2] = fmaf(a2[kk], w1, p1[2]);
      p2[0] = fmaf(a0[kk], w2, p2[0]); p2[1] = fmaf(a1[kk], w2, p2[1]); p2[2] = fmaf(a2[kk], w2, p2[2]);
    }
  }

  // ns1/ns2 = silu(n_es @ W_nsp + b_nsp) split
  float s1a = 0.0f, s2a = 0.0f;
  for (int k = 0; k < 64; k += 4) {
    float a[4];
    ld4(S + 3 * 68 + k, a);
    #pragma unroll
    for (int kk = 0; kk < 4; ++kk) {
      s1a = fmaf(a[kk], W_nsp[(k + kk) * 128 + lane], s1a);
      s2a = fmaf(a[kk], W_nsp[(k + kk) * 128 + 64 + lane], s2a);
    }
  }
  float s1 = silu_f(s1a + b_nsp[lane]);
  float s2 = silu_f(s2a + b_nsp[64 + lane]);

  float nvdot = p1[0] * p2[0] + p1[1] * p2[1] + p1[2] * p2[2];
  float nsu = nvdot * s1 + s2;

  // LayerNorm over 64 features (wave-wide)
  float xs = nsu + node_s[n * 64 + lane];
  float sum = xs, sumsq = xs * xs;
  #pragma unroll
  for (int o = 32; o; o >>= 1) {
    sum += __shfl_xor(sum, o);
    sumsq += __shfl_xor(sumsq, o);
  }
  float mu = sum * (1.0f / 64.0f);
  float var = sumsq * (1.0f / 64.0f) - mu * mu;
  ns_out[n * 64 + lane] = (xs - mu) * rsqrtf(var + 1e-5f) * ln_g[lane] + ln_b[lane];

  // CoorsNorm over 3D axis (lane-local)
  float vv[3];
  #pragma unroll
  for (int dd = 0; dd < 3; ++dd) vv[dd] = nvu[dd] + node_v[n * 192 + dd * 64 + lane];
  float vn2 = sqrtf(vv[0] * vv[0] + vv[1] * vv[1] + vv[2] * vv[2]);
  float scale = cn_s[lane] / fmaxf(vn2, 1e-8f);
  #pragma unroll
  for (int dd = 0; dd < 3; ++dd)
    nv_out[n * 192 + dd * 64 + lane] = vv[dd] * scale;
}

extern "C" void kernel_launch(void* const* d_in, const int* in_sizes, int n_in,
                              void* d_out, int out_size, void* d_ws, size_t ws_size,
                              hipStream_t stream) {
  const float* node_s = (const float*)d_in[0];
  const float* node_v = (const float*)d_in[1];
  const float* edge_s = (const float*)d_in[2];
  const float* edge_v = (const float*)d_in[3];
  const float* dist   = (const float*)d_in[4];
  const float* vctr   = (const float*)d_in[5];
  const int*   src    = (const int*)d_in[6];
  const int*   dst    = (const int*)d_in[7];
  const float* W_nn = (const float*)d_in[8];  const float* b_nn = (const float*)d_in[9];
  const float* W_ep = (const float*)d_in[10]; const float* b_ep = (const float*)d_in[11];
  const float* W_g1 = (const float*)d_in[12]; const float* b_g1 = (const float*)d_in[13];
  const float* W_g2 = (const float*)d_in[14]; const float* b_g2 = (const float*)d_in[15];
  const float* W_ev = (const float*)d_in[16]; const float* b_ev = (const float*)d_in[17];
  const float* W_nvout = (const float*)d_in[18];
  const float* W_nvc = (const float*)d_in[19]; const float* b_nvc = (const float*)d_in[20];
  const float* W_nvp = (const float*)d_in[21];
  const float* W_nsp = (const float*)d_in[22]; const float* b_nsp = (const float*)d_in[23];
  const float* ln_g = (const float*)d_in[24]; const float* ln_b = (const float*)d_in[25];
  const float* cn_s = (const float*)d_in[26];

  const int N = in_sizes[0] / 64;
  const int E = in_sizes[2] / 64;

  float* out    = (float*)d_out;
  float* ns_out = out;
  float* nv_out = out + (size_t)N * 64;
  float* es_out = out + (size_t)N * 256;
  float* ev_out = out + (size_t)N * 256 + (size_t)E * 64;

  // ws layout: ints | bf16 weights | raw bf16 updates (CSR-SLOT order; ev as 3 dd-planes)
  int* cnt      = (int*)d_ws;          // N (histogram, then cursor)
  int* rowstart = cnt + N;             // N+1
  int* epos     = rowstart + N + 1;    // E
  int* elist    = epos + E;            // E (fallback only)
  int* bsum     = elist + E;           // 64 (scan block sums)
  unsigned short* wnn_t = (unsigned short*)(bsum + 64);  // 64x128
  unsigned short* wep_t = wnn_t + 64 * 128;              // 64x64
  unsigned short* wg1_t = wep_t + 64 * 64;
  unsigned short* wg2_t = wg1_t + 64 * 64;
  unsigned short* wev_t = wg2_t + 64 * 64;               // 192x64
  size_t wend = (size_t)((char*)(wev_t + 192 * 64) - (char*)d_ws);
  size_t rawofs = (wend + 255) & ~(size_t)255;
  unsigned short* raw_es = (unsigned short*)((char*)d_ws + rawofs);  // E*64
  unsigned short* raw_ev = raw_es + (size_t)E * 64;                  // 3 * E*64 (dd-planes)
  size_t need = rawofs + (size_t)E * 256 * sizeof(unsigned short);
  int use_raw = (ws_size >= need) ? 1 : 0;

  const int nscan = (N + 1023) / 1024;

  hipMemsetAsync(cnt, 0, (size_t)N * sizeof(int), stream);
  hist_kernel<<<(E + 255) / 256, 256, 0, stream>>>(dst, cnt, E);
  scan1_kernel<<<nscan, 1024, 0, stream>>>(cnt, rowstart, bsum, N);
  scan2_kernel<<<1, 64, 0, stream>>>(bsum, nscan);
  scan3_kernel<<<nscan, 1024, 0, stream>>>(rowstart, cnt, bsum, N, E);
  scatter_kernel<<<(E + 255) / 256, 256, 0, stream>>>(dst, cnt, elist, epos, E);

  wprep_all<<<128, 256, 0, stream>>>(W_nn, W_ep, W_g1, W_g2, W_ev,
                                     wnn_t, wep_t, wg1_t, wg2_t, wev_t);

  int n_tiles = (E + 15) / 16;
  edge_kernel<<<(n_tiles + 3) / 4, 256, 0, stream>>>(
      node_s, node_v, edge_s, edge_v, dist, vctr, src, dst, epos,
      wnn_t, b_nn, wep_t, b_ep, wg1_t, b_g1, wg2_t, b_g2, wev_t, b_ev,
      es_out, ev_out, raw_es, raw_ev, use_raw, E, n_tiles);

  node_kernel<<<(N + 3) / 4, 256, 0, stream>>>(
      node_s, node_v, edge_s, edge_v, es_out, ev_out, raw_es, raw_ev,
      rowstart, elist, use_raw,
      W_nvout, W_nvc, b_nvc, W_nvp, W_nsp, b_nsp,
      ln_g, ln_b, cn_s, ns_out, nv_out, N, E);
}

// Round 11
// 940.475 us; speedup vs baseline: 1.7465x; 1.6526x over previous
//
#include <hip/hip_runtime.h>
#include <hip/hip_bf16.h>
#include <math.h>

typedef __attribute__((ext_vector_type(8))) short bf16x8;
typedef __attribute__((ext_vector_type(4))) float f32x4;

#define MFMA16(a, b, c) __builtin_amdgcn_mfma_f32_16x16x32_bf16((a), (b), (c), 0, 0, 0)

__device__ __forceinline__ float silu_f(float x) { return x / (1.0f + expf(-x)); }

__device__ __forceinline__ unsigned short f2bf(float f) {
  union { __hip_bfloat16 h; unsigned short u; } c;
  c.h = __float2bfloat16(f);
  return c.u;
}
__device__ __forceinline__ unsigned pk2(float a, float b) {
  return (unsigned)f2bf(a) | ((unsigned)f2bf(b) << 16);
}
__device__ __forceinline__ float bfu(unsigned short u) {
  union { unsigned u32; float f; } c;
  c.u32 = (unsigned)u << 16;
  return c.f;
}

// activation fragment (B-operand): lane holds col m=lane&15, k = ks*32 + (lane>>4)*8 ..+7
__device__ __forceinline__ bf16x8 ld_act(const unsigned short* buf, int strideB, int ks, int lane) {
  int row = lane & 15;
  int off = row * strideB + ks * 64 + ((lane >> 4) << 4);
  off ^= (row & 7) << 4;
  return *(const bf16x8*)((const char*)buf + off);
}

// weight fragment (A-operand): lane holds row n=rowbase+(lane&15); Wt row-major [n][K] bf16
__device__ __forceinline__ bf16x8 ld_w(const unsigned short* Wt, int rowbase, int strideB, int ks, int lane) {
  return *(const bf16x8*)((const char*)Wt + (size_t)(rowbase + (lane & 15)) * strideB + ks * 64 + ((lane >> 4) << 4));
}

// ============ fused weight prep: Wt[n][k] = bf16(W[k][n]) ============
__global__ void wprep_all(const float* __restrict__ W_nn, const float* __restrict__ W_ep,
                          const float* __restrict__ W_g1, const float* __restrict__ W_g2,
                          const float* __restrict__ W_ev,
                          unsigned short* __restrict__ wnn_t, unsigned short* __restrict__ wep_t,
                          unsigned short* __restrict__ wg1_t, unsigned short* __restrict__ wg2_t,
                          unsigned short* __restrict__ wev_t) {
  int idx = blockIdx.x * 256 + threadIdx.x;  // 0..32767
  if (idx < 8192) {
    int n = idx >> 7, k = idx & 127;
    wnn_t[idx] = f2bf(W_nn[k * 64 + n]);
  } else if (idx < 12288) {
    int t = idx - 8192; int n = t >> 6, k = t & 63;
    wep_t[t] = f2bf(W_ep[k * 64 + n]);
  } else if (idx < 16384) {
    int t = idx - 12288; int n = t >> 6, k = t & 63;
    wg1_t[t] = f2bf(W_g1[k * 64 + n]);
  } else if (idx < 20480) {
    int t = idx - 16384; int n = t >> 6, k = t & 63;
    wg2_t[t] = f2bf(W_g2[k * 64 + n]);
  } else if (idx < 32768) {
    int t = idx - 20480; int n = t >> 6, k = t & 63;
    wev_t[t] = f2bf(W_ev[k * 192 + n]);
  }
}

// ============ CSR build ============
__global__ void hist_kernel(const int* __restrict__ dst, int* __restrict__ cnt, int E) {
  int i = blockIdx.x * blockDim.x + threadIdx.x;
  if (i < E) atomicAdd(&cnt[dst[i]], 1);
}

__global__ __launch_bounds__(1024) void scan1_kernel(const int* __restrict__ cnt,
                                                     int* __restrict__ rowstart,
                                                     int* __restrict__ bsum, int N) {
  __shared__ int wsum[16];
  const int tid = threadIdx.x;
  const int wv = tid >> 6;
  const int i = blockIdx.x * 1024 + tid;
  int v = (i < N) ? cnt[i] : 0;
  int x = v;
  #pragma unroll
  for (int o = 1; o < 64; o <<= 1) {
    int y = __shfl_up(x, o);
    if ((tid & 63) >= o) x += y;
  }
  if ((tid & 63) == 63) wsum[wv] = x;
  __syncthreads();
  if (tid < 16) {
    int s = wsum[tid];
    #pragma unroll
    for (int o = 1; o < 16; o <<= 1) {
      int y = __shfl_up(s, o);
      if (tid >= o) s += y;
    }
    wsum[tid] = s;
  }
  __syncthreads();
  int woff = (wv > 0) ? wsum[wv - 1] : 0;
  if (i < N) rowstart[i] = woff + x - v;
  if (tid == 0) bsum[blockIdx.x] = wsum[15];
}

__global__ void scan2_kernel(int* __restrict__ bsum, int nb) {
  const int tid = threadIdx.x;
  int v = (tid < nb) ? bsum[tid] : 0;
  int x = v;
  #pragma unroll
  for (int o = 1; o < 64; o <<= 1) {
    int y = __shfl_up(x, o);
    if (tid >= o) x += y;
  }
  if (tid < nb) bsum[tid] = x - v;
}

__global__ __launch_bounds__(1024) void scan3_kernel(int* __restrict__ rowstart,
                                                     int* __restrict__ cursor,
                                                     const int* __restrict__ bsum,
                                                     int N, int E) {
  const int i = blockIdx.x * 1024 + threadIdx.x;
  if (i < N) {
    int r = rowstart[i] + bsum[blockIdx.x];
    rowstart[i] = r;
    cursor[i] = r;
  }
  if (i == 0) rowstart[N] = E;
}

__global__ void scatter_kernel(const int* __restrict__ dst, int* __restrict__ cursor,
                               int* __restrict__ elist, int* __restrict__ epos, int E) {
  int i = blockIdx.x * blockDim.x + threadIdx.x;
  if (i < E) {
    int pos = atomicAdd(&cursor[dst[i]], 1);
    elist[pos] = i;
    epos[i] = pos;
  }
}

// ============ edge kernel (GOLDEN r7): bf16 MFMA chain; raw bf16 full-line SLOT-order writes ============
// launch_bounds(256,4): VGPR cap 64 == true pressure. LESSON (r8-r10): forcing the cap below
// true pressure (32/42) creates scratch spills -> +2.5-2.9GB symmetric FETCH/WRITE and 2x time,
// even though occupancy rises. Raw stores REGULAR (L2 merges 8x16B into one dirty line).
__global__ __launch_bounds__(256, 4) void edge_kernel(
    const float* __restrict__ node_s, const float* __restrict__ node_v,
    const float* __restrict__ edge_s, const float* __restrict__ edge_v,
    const float* __restrict__ dist,   const float* __restrict__ vctr,
    const int* __restrict__ src,      const int* __restrict__ dst,
    const int* __restrict__ epos,
    const unsigned short* __restrict__ wnn_t, const float* __restrict__ b_nn,
    const unsigned short* __restrict__ wep_t, const float* __restrict__ b_ep,
    const unsigned short* __restrict__ wg1_t, const float* __restrict__ b_g1,
    const unsigned short* __restrict__ wg2_t, const float* __restrict__ b_g2,
    const unsigned short* __restrict__ wev_t, const float* __restrict__ b_ev,
    float* __restrict__ es_out, float* __restrict__ ev_out,
    unsigned short* __restrict__ raw_es, unsigned short* __restrict__ raw_ev,
    int use_raw, int E, int n_tiles)
{
  __shared__ __align__(16) unsigned short lds[4 * 2048]; // 16KB/block
  const int wid  = threadIdx.x >> 6;
  const int lane = threadIdx.x & 63;
  const int tile = blockIdx.x * 4 + wid;
  if (tile >= n_tiles) return;
  const int ebase = tile * 16;
  unsigned short* bufA = lds + wid * 2048;
  const size_t Estride = (size_t)E * 64;

  const int m  = lane & 15;   // edge within tile (compute phase)
  const int nb = lane >> 4;   // feature sub-block (n = nt*16 + nb*4 + q)

  // ---- stage node_s[src] -> bufA[:,0:64], node_s[dst] -> bufA[:,64:128] ----
  {
    const int sm = lane >> 5;
    const int kk = lane & 31;
    #pragma unroll
    for (int p = 0; p < 8; ++p) {
      int le = p * 2 + sm;
      int e = ebase + le; if (e >= E) e = E - 1;
      int s = src[e], d = dst[e];
      float2 vs = *(const float2*)(node_s + (size_t)s * 64 + 2 * kk);
      float2 vd = *(const float2*)(node_s + (size_t)d * 64 + 2 * kk);
      unsigned swz = (le & 7) << 4;
      *(unsigned*)((char*)bufA + ((le * 256 + kk * 4) ^ swz))       = pk2(vs.x, vs.y);
      *(unsigned*)((char*)bufA + ((le * 256 + 128 + kk * 4) ^ swz)) = pk2(vd.x, vd.y);
    }
  }
  __builtin_amdgcn_wave_barrier();

  const int e = (ebase + m < E) ? ebase + m : E - 1;
  const float dd_ = dist[e];
  const float cc = (dd_ < 5.0f) ? 0.5f * (cosf(3.14159265358979f * dd_ * 0.2f) + 1.0f) : 0.0f;
  const int s_nd = src[e];

  const f32x4 z4 = {0.0f, 0.0f, 0.0f, 0.0f};
  const unsigned swzm = (m & 7) << 4;

  // transpose-write lane roles (8 lanes x 16B = one full 128B row per edge)
  const int tme  = lane >> 3;      // edge 0..7 (+8 for second half)
  const int tseg = lane & 7;       // 16B segment within row
  int tpos0 = -1, tpos1 = -1;
  if (use_raw) {
    if (ebase + tme < E)     tpos0 = epos[ebase + tme];
    if (ebase + 8 + tme < E) tpos1 = epos[ebase + 8 + tme];
  }

  // A-fragments of [src|dst] (K=128) — load before bufA gets overwritten
  bf16x8 a0 = ld_act(bufA, 256, 0, lane), a1 = ld_act(bufA, 256, 1, lane);
  bf16x8 a2 = ld_act(bufA, 256, 2, lane), a3 = ld_act(bufA, 256, 3, lane);

  // B-fragments of edge_s (K=64) directly from global (contiguous k-slices of own row)
  const float* esrow = edge_s + (size_t)e * 64;
  bf16x8 b0, b1;
  {
    const int k8 = (lane >> 4) << 3;
    f32x4 p0 = *(const f32x4*)(esrow + k8);
    f32x4 p1 = *(const f32x4*)(esrow + k8 + 4);
    f32x4 q0 = *(const f32x4*)(esrow + 32 + k8);
    f32x4 q1 = *(const f32x4*)(esrow + 32 + k8 + 4);
    union { bf16x8 v; uint4 u; } cb;
    cb.u.x = pk2(p0.x, p0.y); cb.u.y = pk2(p0.z, p0.w);
    cb.u.z = pk2(p1.x, p1.y); cb.u.w = pk2(p1.z, p1.w);
    b0 = cb.v;
    cb.u.x = pk2(q0.x, q0.y); cb.u.y = pk2(q0.z, q0.w);
    cb.u.z = pk2(q1.x, q1.y); cb.u.w = pk2(q1.z, q1.w);
    b1 = cb.v;
  }
  __builtin_amdgcn_wave_barrier();

  // ---- nn & ep per n-tile, fuse to em, write to bufA[16][64] ----
  #pragma unroll
  for (int nt = 0; nt < 4; ++nt) {
    f32x4 aN = z4, aP = z4;
    aN = MFMA16(ld_w(wnn_t, nt * 16, 256, 0, lane), a0, aN);
    aN = MFMA16(ld_w(wnn_t, nt * 16, 256, 1, lane), a1, aN);
    aN = MFMA16(ld_w(wnn_t, nt * 16, 256, 2, lane), a2, aN);
    aN = MFMA16(ld_w(wnn_t, nt * 16, 256, 3, lane), a3, aN);
    aP = MFMA16(ld_w(wep_t, nt * 16, 128, 0, lane), b0, aP);
    aP = MFMA16(ld_w(wep_t, nt * 16, 128, 1, lane), b1, aP);
    f32x4 bn = *(const f32x4*)(b_nn + nt * 16 + nb * 4);
    f32x4 bp = *(const f32x4*)(b_ep + nt * 16 + nb * 4);
    float e0 = (aN.x + bn.x) * (aP.x + bp.x);
    float e1 = (aN.y + bn.y) * (aP.y + bp.y);
    float e2 = (aN.z + bn.z) * (aP.z + bp.z);
    float e3 = (aN.w + bn.w) * (aP.w + bp.w);
    uint2 w2; w2.x = pk2(e0, e1); w2.y = pk2(e2, e3);
    *(uint2*)((char*)bufA + ((m * 128 + nt * 32 + nb * 8) ^ swzm)) = w2;
  }
  __builtin_amdgcn_wave_barrier();

  // ---- h = silu(em @ W_g1 + b_g1) ----
  bf16x8 c0 = ld_act(bufA, 128, 0, lane), c1 = ld_act(bufA, 128, 1, lane);
  __builtin_amdgcn_wave_barrier();
  #pragma unroll
  for (int nt = 0; nt < 4; ++nt) {
    f32x4 aH = z4;
    aH = MFMA16(ld_w(wg1_t, nt * 16, 128, 0, lane), c0, aH);
    aH = MFMA16(ld_w(wg1_t, nt * 16, 128, 1, lane), c1, aH);
    f32x4 bg = *(const f32x4*)(b_g1 + nt * 16 + nb * 4);
    uint2 w2;
    w2.x = pk2(silu_f(aH.x + bg.x), silu_f(aH.y + bg.y));
    w2.y = pk2(silu_f(aH.z + bg.z), silu_f(aH.w + bg.w));
    *(uint2*)((char*)bufA + ((m * 128 + nt * 32 + nb * 8) ^ swzm)) = w2;
  }
  __builtin_amdgcn_wave_barrier();

  // ---- es_upd = (h @ W_g2 + b_g2) * c ; es_out = es_upd + edge_s ; pack es_upd -> bufA ----
  bf16x8 d0 = ld_act(bufA, 128, 0, lane), d1 = ld_act(bufA, 128, 1, lane);
  __builtin_amdgcn_wave_barrier();
  float* eorow = es_out + (size_t)e * 64;
  #pragma unroll
  for (int nt = 0; nt < 4; ++nt) {
    f32x4 aS = z4;
    aS = MFMA16(ld_w(wg2_t, nt * 16, 128, 0, lane), d0, aS);
    aS = MFMA16(ld_w(wg2_t, nt * 16, 128, 1, lane), d1, aS);
    f32x4 bg = *(const f32x4*)(b_g2 + nt * 16 + nb * 4);
    float u0 = (aS.x + bg.x) * cc, u1 = (aS.y + bg.y) * cc;
    float u2 = (aS.z + bg.z) * cc, u3 = (aS.w + bg.w) * cc;
    const int n0 = nt * 16 + nb * 4;
    uint2 w2; w2.x = pk2(u0, u1); w2.y = pk2(u2, u3);
    *(uint2*)((char*)bufA + ((m * 128 + nt * 32 + nb * 8) ^ swzm)) = w2;
    if (ebase + m < E) {
      f32x4 r = *(const f32x4*)(esrow + n0);
      f32x4 o; o.x = u0 + r.x; o.y = u1 + r.y; o.z = u2 + r.z; o.w = u3 + r.w;
      __builtin_nontemporal_store(o, (f32x4*)(eorow + n0));
    }
  }
  __builtin_amdgcn_wave_barrier();

  // ---- es_upd act fragments + raw_es full-line slot-order write (both read bufA) ----
  bf16x8 g0 = ld_act(bufA, 128, 0, lane), g1f = ld_act(bufA, 128, 1, lane);
  if (use_raw) {
    if (tpos0 >= 0) {
      bf16x8 row = *(const bf16x8*)((const char*)bufA + ((tme * 128 + tseg * 16) ^ ((tme & 7) << 4)));
      *(bf16x8*)(raw_es + (size_t)tpos0 * 64 + tseg * 8) = row;
    }
    if (tpos1 >= 0) {
      bf16x8 row = *(const bf16x8*)((const char*)bufA + (((8 + tme) * 128 + tseg * 16) ^ (((8 + tme) & 7) << 4)));
      *(bf16x8*)(raw_es + (size_t)tpos1 * 64 + tseg * 8) = row;
    }
  }

  // ---- vch = es_upd @ W_ev + b_ev : all 12 accumulators live (VGPR 64 @ cap 64, no spill) ----
  f32x4 accV[12];
  #pragma unroll
  for (int ch = 0; ch < 3; ++ch)
    #pragma unroll
    for (int nt = 0; nt < 4; ++nt) {
      f32x4 a = z4;
      a = MFMA16(ld_w(wev_t, ch * 64 + nt * 16, 128, 0, lane), g0,  a);
      a = MFMA16(ld_w(wev_t, ch * 64 + nt * 16, 128, 1, lane), g1f, a);
      f32x4 bv = *(const f32x4*)(b_ev + ch * 64 + nt * 16 + nb * 4);
      a.x += bv.x; a.y += bv.y; a.z += bv.z; a.w += bv.w;
      accV[ch * 4 + nt] = a;
    }

  // ---- ev_upd per dd-plane: compute, store ev_out, pack -> bufA, transpose-write raw plane ----
  const float* nvb = node_v + (size_t)s_nd * 192;
  const float* evb = edge_v + (size_t)e * 192;
  float* eob = ev_out + (size_t)e * 192;
  const float vnn[3] = {vctr[e * 3], vctr[e * 3 + 1], vctr[e * 3 + 2]};
  const bool live = (ebase + m < E);
  #pragma unroll
  for (int dd = 0; dd < 3; ++dd) {
    __builtin_amdgcn_wave_barrier();
    #pragma unroll
    for (int nt = 0; nt < 4; ++nt) {
      const int n0 = nt * 16 + nb * 4;
      f32x4 nv = *(const f32x4*)(nvb + dd * 64 + n0);
      f32x4 ev = __builtin_nontemporal_load((const f32x4*)(evb + dd * 64 + n0));
      float eu0 = (nv.x * accV[nt].x + ev.x * accV[4 + nt].x + vnn[dd] * accV[8 + nt].x) * cc;
      float eu1 = (nv.y * accV[nt].y + ev.y * accV[4 + nt].y + vnn[dd] * accV[8 + nt].y) * cc;
      float eu2 = (nv.z * accV[nt].z + ev.z * accV[4 + nt].z + vnn[dd] * accV[8 + nt].z) * cc;
      float eu3 = (nv.w * accV[nt].w + ev.w * accV[4 + nt].w + vnn[dd] * accV[8 + nt].w) * cc;
      if (live) {
        f32x4 o; o.x = eu0 + ev.x; o.y = eu1 + ev.y; o.z = eu2 + ev.z; o.w = eu3 + ev.w;
        __builtin_nontemporal_store(o, (f32x4*)(eob + dd * 64 + n0));
      }
      uint2 w2; w2.x = pk2(eu0, eu1); w2.y = pk2(eu2, eu3);
      *(uint2*)((char*)bufA + ((m * 128 + nt * 32 + nb * 8) ^ swzm)) = w2;
    }
    __builtin_amdgcn_wave_barrier();
    if (use_raw) {
      unsigned short* plane = raw_ev + (size_t)dd * Estride;
      if (tpos0 >= 0) {
        bf16x8 row = *(const bf16x8*)((const char*)bufA + ((tme * 128 + tseg * 16) ^ ((tme & 7) << 4)));
        *(bf16x8*)(plane + (size_t)tpos0 * 64 + tseg * 8) = row;
      }
      if (tpos1 >= 0) {
        bf16x8 row = *(const bf16x8*)((const char*)bufA + (((8 + tme) * 128 + tseg * 16) ^ (((8 + tme) & 7) << 4)));
        *(bf16x8*)(plane + (size_t)tpos1 * 64 + tseg * 8) = row;
      }
    }
  }
}

// ============ node kernel: SEQUENTIAL slot-order aggregation + node update ============
__device__ __forceinline__ void ld4(const float* p, float o[4]) {
  f32x4 v = *(const f32x4*)p;
  o[0] = v.x; o[1] = v.y; o[2] = v.z; o[3] = v.w;
}

__global__ __launch_bounds__(256) void node_kernel(
    const float* __restrict__ node_s, const float* __restrict__ node_v,
    const float* __restrict__ edge_s, const float* __restrict__ edge_v,
    const float* __restrict__ es_r,   const float* __restrict__ ev_r,
    const unsigned short* __restrict__ raw_es, const unsigned short* __restrict__ raw_ev,
    const int* __restrict__ rowstart, const int* __restrict__ elist, int use_raw,
    const float* __restrict__ W_nvout,
    const float* __restrict__ W_nvc, const float* __restrict__ b_nvc,
    const float* __restrict__ W_nvp,
    const float* __restrict__ W_nsp, const float* __restrict__ b_nsp,
    const float* __restrict__ ln_g, const float* __restrict__ ln_b,
    const float* __restrict__ cn_s,
    float* __restrict__ ns_out, float* __restrict__ nv_out, int N, int E)
{
  __shared__ __align__(16) float scm[4 * 8 * 68];
  const int wid = threadIdx.x >> 6, lane = threadIdx.x & 63;
  const int n = blockIdx.x * 4 + wid;
  if (n >= N) return;
  float* S = &scm[wid * 8 * 68];

  const int rs = rowstart[n], re = rowstart[n + 1];
  float nes = 0.0f, nev0 = 0.0f, nev1 = 0.0f, nev2 = 0.0f;
  if (use_raw) {
    const size_t Estride = (size_t)E * 64;
    const unsigned short* pe = raw_es + (size_t)rs * 64 + lane;
    const unsigned short* v0 = raw_ev + (size_t)rs * 64 + lane;
    const unsigned short* v1 = v0 + Estride;
    const unsigned short* v2 = v1 + Estride;
    const int cntE = re - rs;
    int i = 0;
    for (; i + 1 < cntE; i += 2) {
      unsigned short e0 = pe[i * 64],  e1 = pe[i * 64 + 64];
      unsigned short a0 = v0[i * 64],  a1 = v0[i * 64 + 64];
      unsigned short b0 = v1[i * 64],  b1 = v1[i * 64 + 64];
      unsigned short c0 = v2[i * 64],  c1 = v2[i * 64 + 64];
      nes  += bfu(e0) + bfu(e1);
      nev0 += bfu(a0) + bfu(a1);
      nev1 += bfu(b0) + bfu(b1);
      nev2 += bfu(c0) + bfu(c1);
    }
    if (i < cntE) {
      nes  += bfu(pe[i * 64]);
      nev0 += bfu(v0[i * 64]); nev1 += bfu(v1[i * 64]); nev2 += bfu(v2[i * 64]);
    }
  } else {
    for (int idx = rs; idx < re; ++idx) {
      int e = elist[idx];
      size_t b64 = (size_t)e * 64, b192 = (size_t)e * 192;
      nes  += es_r[b64 + lane]        - edge_s[b64 + lane];
      nev0 += ev_r[b192 + lane]       - edge_v[b192 + lane];
      nev1 += ev_r[b192 + 64 + lane]  - edge_v[b192 + 64 + lane];
      nev2 += ev_r[b192 + 128 + lane] - edge_v[b192 + 128 + lane];
    }
  }
  const float inv = 1.0f / fmaxf((float)(re - rs), 1.0f);
  nes *= inv; nev0 *= inv; nev1 *= inv; nev2 *= inv;

  S[0 * 68 + lane] = nev0; S[1 * 68 + lane] = nev1;
  S[2 * 68 + lane] = nev2; S[3 * 68 + lane] = nes;
  __builtin_amdgcn_wave_barrier();

  // n_ev @ W_nvout -> o1,o2,o3
  float o1[3] = {}, o2[3] = {}, o3[3] = {};
  for (int k = 0; k < 64; k += 4) {
    float a0[4], a1[4], a2[4];
    ld4(S + 0 * 68 + k, a0); ld4(S + 1 * 68 + k, a1); ld4(S + 2 * 68 + k, a2);
    #pragma unroll
    for (int kk = 0; kk < 4; ++kk) {
      float w0 = W_nvout[(k + kk) * 192 + lane];
      float w1 = W_nvout[(k + kk) * 192 + 64 + lane];
      float w2 = W_nvout[(k + kk) * 192 + 128 + lane];
      o1[0] = fmaf(a0[kk], w0, o1[0]); o1[1] = fmaf(a1[kk], w0, o1[1]); o1[2] = fmaf(a2[kk], w0, o1[2]);
      o2[0] = fmaf(a0[kk], w1, o2[0]); o2[1] = fmaf(a1[kk], w1, o2[1]); o2[2] = fmaf(a2[kk], w1, o2[2]);
      o3[0] = fmaf(a0[kk], w2, o3[0]); o3[1] = fmaf(a1[kk], w2, o3[1]); o3[2] = fmaf(a2[kk], w2, o3[2]);
    }
  }
  float nrm = sqrtf(o3[0] * o3[0] + o3[1] * o3[1] + o3[2] * o3[2]);
  S[4 * 68 + lane] = nrm;
  __builtin_amdgcn_wave_barrier();

  // v_channel = [n_es | ||o3||] @ W_nvc + b_nvc
  float vch = 0.0f;
  for (int k = 0; k < 64; k += 4) {
    float a[4], b[4];
    ld4(S + 3 * 68 + k, a); ld4(S + 4 * 68 + k, b);
    #pragma unroll
    for (int kk = 0; kk < 4; ++kk) {
      vch = fmaf(a[kk], W_nvc[(k + kk) * 64 + lane], vch);
      vch = fmaf(b[kk], W_nvc[(64 + k + kk) * 64 + lane], vch);
    }
  }
  vch += b_nvc[lane];

  float nvu[3];
  #pragma unroll
  for (int dd = 0; dd < 3; ++dd) {
    nvu[dd] = o1[dd] * vch + o2[dd];
    S[(5 + dd) * 68 + lane] = nvu[dd];
  }
  __builtin_amdgcn_wave_barrier();

  // nvp1/nvp2 = nv_upd @ W_nvp (split)
  float p1[3] = {}, p2[3] = {};
  for (int k = 0; k < 64; k += 4) {
    float a0[4], a1[4], a2[4];
    ld4(S + 5 * 68 + k, a0); ld4(S + 6 * 68 + k, a1); ld4(S + 7 * 68 + k, a2);
    #pragma unroll
    for (int kk = 0; kk < 4; ++kk) {
      float w1 = W_nvp[(k + kk) * 128 + lane];
      float w2 = W_nvp[(k + kk) * 128 + 64 + lane];
      p1[0] = fmaf(a0[kk], w1, p1[0]); p1[1] = fmaf(a1[kk], w1, p1[1]); p1[2] = fmaf(a2[kk], w1, p1[2]);
      p2[0] = fmaf(a0[kk], w2, p2[0]); p2[1] = fmaf(a1[kk], w2, p2[1]); p2[2] = fmaf(a2[kk], w2, p2[2]);
    }
  }

  // ns1/ns2 = silu(n_es @ W_nsp + b_nsp) split
  float s1a = 0.0f, s2a = 0.0f;
  for (int k = 0; k < 64; k += 4) {
    float a[4];
    ld4(S + 3 * 68 + k, a);
    #pragma unroll
    for (int kk = 0; kk < 4; ++kk) {
      s1a = fmaf(a[kk], W_nsp[(k + kk) * 128 + lane], s1a);
      s2a = fmaf(a[kk], W_nsp[(k + kk) * 128 + 64 + lane], s2a);
    }
  }
  float s1 = silu_f(s1a + b_nsp[lane]);
  float s2 = silu_f(s2a + b_nsp[64 + lane]);

  float nvdot = p1[0] * p2[0] + p1[1] * p2[1] + p1[2] * p2[2];
  float nsu = nvdot * s1 + s2;

  // LayerNorm over 64 features (wave-wide)
  float xs = nsu + node_s[n * 64 + lane];
  float sum = xs, sumsq = xs * xs;
  #pragma unroll
  for (int o = 32; o; o >>= 1) {
    sum += __shfl_xor(sum, o);
    sumsq += __shfl_xor(sumsq, o);
  }
  float mu = sum * (1.0f / 64.0f);
  float var = sumsq * (1.0f / 64.0f) - mu * mu;
  ns_out[n * 64 + lane] = (xs - mu) * rsqrtf(var + 1e-5f) * ln_g[lane] + ln_b[lane];

  // CoorsNorm over 3D axis (lane-local)
  float vv[3];
  #pragma unroll
  for (int dd = 0; dd < 3; ++dd) vv[dd] = nvu[dd] + node_v[n * 192 + dd * 64 + lane];
  float vn2 = sqrtf(vv[0] * vv[0] + vv[1] * vv[1] + vv[2] * vv[2]);
  float scale = cn_s[lane] / fmaxf(vn2, 1e-8f);
  #pragma unroll
  for (int dd = 0; dd < 3; ++dd)
    nv_out[n * 192 + dd * 64 + lane] = vv[dd] * scale;
}

extern "C" void kernel_launch(void* const* d_in, const int* in_sizes, int n_in,
                              void* d_out, int out_size, void* d_ws, size_t ws_size,
                              hipStream_t stream) {
  const float* node_s = (const float*)d_in[0];
  const float* node_v = (const float*)d_in[1];
  const float* edge_s = (const float*)d_in[2];
  const float* edge_v = (const float*)d_in[3];
  const float* dist   = (const float*)d_in[4];
  const float* vctr   = (const float*)d_in[5];
  const int*   src    = (const int*)d_in[6];
  const int*   dst    = (const int*)d_in[7];
  const float* W_nn = (const float*)d_in[8];  const float* b_nn = (const float*)d_in[9];
  const float* W_ep = (const float*)d_in[10]; const float* b_ep = (const float*)d_in[11];
  const float* W_g1 = (const float*)d_in[12]; const float* b_g1 = (const float*)d_in[13];
  const float* W_g2 = (const float*)d_in[14]; const float* b_g2 = (const float*)d_in[15];
  const float* W_ev = (const float*)d_in[16]; const float* b_ev = (const float*)d_in[17];
  const float* W_nvout = (const float*)d_in[18];
  const float* W_nvc = (const float*)d_in[19]; const float* b_nvc = (const float*)d_in[20];
  const float* W_nvp = (const float*)d_in[21];
  const float* W_nsp = (const float*)d_in[22]; const float* b_nsp = (const float*)d_in[23];
  const float* ln_g = (const float*)d_in[24]; const float* ln_b = (const float*)d_in[25];
  const float* cn_s = (const float*)d_in[26];

  const int N = in_sizes[0] / 64;
  const int E = in_sizes[2] / 64;

  float* out    = (float*)d_out;
  float* ns_out = out;
  float* nv_out = out + (size_t)N * 64;
  float* es_out = out + (size_t)N * 256;
  float* ev_out = out + (size_t)N * 256 + (size_t)E * 64;

  // ws layout: ints | bf16 weights | raw bf16 updates (CSR-SLOT order; ev as 3 dd-planes)
  int* cnt      = (int*)d_ws;          // N (histogram, then cursor)
  int* rowstart = cnt + N;             // N+1
  int* epos     = rowstart + N + 1;    // E
  int* elist    = epos + E;            // E (fallback only)
  int* bsum     = elist + E;           // 64 (scan block sums)
  unsigned short* wnn_t = (unsigned short*)(bsum + 64);  // 64x128
  unsigned short* wep_t = wnn_t + 64 * 128;              // 64x64
  unsigned short* wg1_t = wep_t + 64 * 64;
  unsigned short* wg2_t = wg1_t + 64 * 64;
  unsigned short* wev_t = wg2_t + 64 * 64;               // 192x64
  size_t wend = (size_t)((char*)(wev_t + 192 * 64) - (char*)d_ws);
  size_t rawofs = (wend + 255) & ~(size_t)255;
  unsigned short* raw_es = (unsigned short*)((char*)d_ws + rawofs);  // E*64
  unsigned short* raw_ev = raw_es + (size_t)E * 64;                  // 3 * E*64 (dd-planes)
  size_t need = rawofs + (size_t)E * 256 * sizeof(unsigned short);
  int use_raw = (ws_size >= need) ? 1 : 0;

  const int nscan = (N + 1023) / 1024;

  hipMemsetAsync(cnt, 0, (size_t)N * sizeof(int), stream);
  hist_kernel<<<(E + 255) / 256, 256, 0, stream>>>(dst, cnt, E);
  scan1_kernel<<<nscan, 1024, 0, stream>>>(cnt, rowstart, bsum, N);
  scan2_kernel<<<1, 64, 0, stream>>>(bsum, nscan);
  scan3_kernel<<<nscan, 1024, 0, stream>>>(rowstart, cnt, bsum, N, E);
  scatter_kernel<<<(E + 255) / 256, 256, 0, stream>>>(dst, cnt, elist, epos, E);

  wprep_all<<<128, 256, 0, stream>>>(W_nn, W_ep, W_g1, W_g2, W_ev,
                                     wnn_t, wep_t, wg1_t, wg2_t, wev_t);

  int n_tiles = (E + 15) / 16;
  edge_kernel<<<(n_tiles + 3) / 4, 256, 0, stream>>>(
      node_s, node_v, edge_s, edge_v, dist, vctr, src, dst, epos,
      wnn_t, b_nn, wep_t, b_ep, wg1_t, b_g1, wg2_t, b_g2, wev_t, b_ev,
      es_out, ev_out, raw_es, raw_ev, use_raw, E, n_tiles);

  node_kernel<<<(N + 3) / 4, 256, 0, stream>>>(
      node_s, node_v, edge_s, edge_v, es_out, ev_out, raw_es, raw_ev,
      rowstart, elist, use_raw,
      W_nvout, W_nvc, b_nvc, W_nvp, W_nsp, b_nsp,
      ln_g, ln_b, cn_s, ns_out, nv_out, N, E);
}